// Round 1
// baseline (7058.848 us; speedup 1.0000x reference)
//
#include <hip/hip_runtime.h>
#include <hip/hip_bf16.h>

// Problem constants
#define BB 128
#define TT 1024
#define II 256
#define HH 512
#define CC 32

// RNN W_hh residency split (k-tiles of 32 along K=512 -> 16 k-tiles)
#define KRR 8   // k-tiles held in VGPRs
#define KLL 4   // k-tiles held in LDS
#define KSS 4   // k-tiles streamed from L2 each step  (KRR+KLL+KSS == 16)

typedef short bf16x8 __attribute__((ext_vector_type(8)));
typedef float f32x4 __attribute__((ext_vector_type(4)));

__device__ __forceinline__ unsigned short f2bf(float f) {
  union { __hip_bfloat16 h; unsigned short u; } cv;
  cv.h = __float2bfloat16(f);
  return cv.u;
}

// ---------------------------------------------------------------------------
// Prep: convert W_hh and W_ih to bf16 in ws; compute cp = cons@W_ch^T + b_ch + b_hh
// ---------------------------------------------------------------------------
__global__ void k_prep(const float* __restrict__ Whh, const float* __restrict__ Wih,
                       const float* __restrict__ cons, const float* __restrict__ Wch,
                       const float* __restrict__ bch, const float* __restrict__ bhh,
                       unsigned short* __restrict__ whh_bf, unsigned short* __restrict__ wih_bf,
                       float* __restrict__ cp) {
  int bid = blockIdx.x, tid = threadIdx.x;
  if (bid < 256) {                       // W_hh: 512*512 = 262144 elems
    int idx = bid * 1024 + tid * 4;
    float4 v = *reinterpret_cast<const float4*>(Whh + idx);
    ushort4 u = make_ushort4(f2bf(v.x), f2bf(v.y), f2bf(v.z), f2bf(v.w));
    *reinterpret_cast<ushort4*>(whh_bf + idx) = u;
  } else if (bid < 384) {                // W_ih: 512*256 = 131072 elems
    int idx = (bid - 256) * 1024 + tid * 4;
    float4 v = *reinterpret_cast<const float4*>(Wih + idx);
    ushort4 u = make_ushort4(f2bf(v.x), f2bf(v.y), f2bf(v.z), f2bf(v.w));
    *reinterpret_cast<ushort4*>(wih_bf + idx) = u;
  } else {                               // cp rows, b = bid-384
    int b = bid - 384;
    for (int h = tid; h < HH; h += 256) {
      float s = bch[h] + bhh[h];
      #pragma unroll
      for (int c = 0; c < CC; ++c) s += cons[b * CC + c] * Wch[h * CC + c];
      cp[b * HH + h] = s;
    }
  }
}

// ---------------------------------------------------------------------------
// xp GEMM: out[b][t][h] = sum_i x[b][t][i] * W_ih[h][i] + b_ih[h]
// M = B*T = 131072 (rows of x, row-major K=256), N = 512.
// Tile: BM=64 (4 waves x 16 rows), BN=512 (32 n-tiles/wave), BK=64 x 4 iters.
// ---------------------------------------------------------------------------
__launch_bounds__(256, 2)
__global__ void k_xp(const float* __restrict__ x, const unsigned short* __restrict__ wih_bf,
                     const float* __restrict__ bih, float* __restrict__ out) {
  __shared__ unsigned short As[64 * 64];    // 8 KB  [row][k] swizzled
  __shared__ unsigned short Ws[512 * 64];   // 64 KB [n][k] swizzled
  int tid = threadIdx.x;
  int w = tid >> 6, l = tid & 63, lo = l & 15, hi = l >> 4;
  int m0 = blockIdx.x * 64;

  f32x4 acc[32];
  #pragma unroll
  for (int i = 0; i < 32; ++i) acc[i] = (f32x4){0.f, 0.f, 0.f, 0.f};

  float bias[32];
  #pragma unroll
  for (int nt = 0; nt < 32; ++nt) bias[nt] = bih[nt * 16 + lo];

  char* Asc = reinterpret_cast<char*>(As);
  char* Wsc = reinterpret_cast<char*>(Ws);

  for (int kit = 0; kit < 4; ++kit) {
    int k0 = kit * 64;
    __syncthreads();
    // stage A tile: 64 rows x 64 k, f32 -> bf16
    {
      int r = tid >> 2;            // 0..63
      int kq = (tid & 3) * 16;     // 0,16,32,48
      const float* src = x + (long)(m0 + r) * II + k0 + kq;
      #pragma unroll
      for (int q = 0; q < 4; ++q) {
        float4 v = *reinterpret_cast<const float4*>(src + q * 4);
        ushort4 u = make_ushort4(f2bf(v.x), f2bf(v.y), f2bf(v.z), f2bf(v.w));
        int byte = ((kq + q * 4) * 2) ^ ((r & 7) << 4);
        *reinterpret_cast<ushort4*>(Asc + r * 128 + byte) = u;
      }
    }
    // stage W tile: 512 rows x 64 k (already bf16)
    {
      int rr = tid >> 3;           // 0..31
      int cc = (tid & 7) * 8;      // element offset 0..56
      #pragma unroll
      for (int p = 0; p < 16; ++p) {
        int r = p * 32 + rr;
        uint4 v = *reinterpret_cast<const uint4*>(wih_bf + r * II + k0 + cc);
        int byte = (cc * 2) ^ ((r & 7) << 4);
        *reinterpret_cast<uint4*>(Wsc + r * 128 + byte) = v;
      }
    }
    __syncthreads();
    #pragma unroll
    for (int kt = 0; kt < 2; ++kt) {
      int kbyte = kt * 64 + hi * 16;
      int arow = w * 16 + lo;
      bf16x8 af = *reinterpret_cast<const bf16x8*>(Asc + arow * 128 + (kbyte ^ ((arow & 7) << 4)));
      #pragma unroll
      for (int nt = 0; nt < 32; ++nt) {
        int brow = nt * 16 + lo;
        bf16x8 bfr = *reinterpret_cast<const bf16x8*>(Wsc + brow * 128 + (kbyte ^ ((brow & 7) << 4)));
        acc[nt] = __builtin_amdgcn_mfma_f32_16x16x32_bf16(af, bfr, acc[nt], 0, 0, 0);
      }
    }
  }
  // epilogue: add bias, store f32
  #pragma unroll
  for (int i = 0; i < 4; ++i) {
    float* dst = out + (long)(m0 + w * 16 + hi * 4 + i) * HH + lo;
    #pragma unroll
    for (int nt = 0; nt < 32; ++nt) dst[nt * 16] = acc[nt][i] + bias[nt];
  }
}

// ---------------------------------------------------------------------------
// Recurrence: 8 WGs x 512 threads (8 waves). WG bg owns batches [bg*16, bg*16+16).
// Per step: h_new = tanh(xp + cp + h @ W_hh^T), masked by t < len.
// xp is read from out[b][t][:] and overwritten with the masked output.
// W_hh^T fragments: kt<KRR in VGPRs, next KLL in LDS, last KSS streamed from L2.
// h: [16][512] bf16 in LDS, XOR-swizzled; single buffer, 2 barriers/step;
// masked lanes skip the h-write (h frozen == jnp.where semantics).
// ---------------------------------------------------------------------------
__launch_bounds__(512, 2)
__global__ void k_rnn(float* __restrict__ out,
                      const unsigned short* __restrict__ whh_bf,
                      const float* __restrict__ cp,
                      const int* __restrict__ lengths) {
  __shared__ unsigned short hbuf[16 * 512];               // 16 KB
  __shared__ unsigned short wlds[8 * 4 * KLL * 512];      // 128 KB
  int tid = threadIdx.x;
  int w = tid >> 6, l = tid & 63, lo = l & 15, hi = l >> 4;
  int bbase = blockIdx.x * 16;

  int ncol[4];
  #pragma unroll
  for (int nt = 0; nt < 4; ++nt) ncol[nt] = w * 64 + nt * 16 + lo;

  int len[4];
  #pragma unroll
  for (int i = 0; i < 4; ++i) len[i] = lengths[bbase + hi * 4 + i];

  float cpv[4][4];  // [i][nt]
  #pragma unroll
  for (int i = 0; i < 4; ++i)
    #pragma unroll
    for (int nt = 0; nt < 4; ++nt)
      cpv[i][nt] = cp[(bbase + hi * 4 + i) * HH + ncol[nt]];

  // W fragments in registers: kt in [0, KRR)
  bf16x8 wreg[KRR][4];
  #pragma unroll
  for (int kt = 0; kt < KRR; ++kt)
    #pragma unroll
    for (int nt = 0; nt < 4; ++nt)
      wreg[kt][nt] = *reinterpret_cast<const bf16x8*>(whh_bf + ncol[nt] * HH + kt * 32 + hi * 8);

  // W fragments staged to LDS: kt in [KRR, KRR+KLL)
  #pragma unroll
  for (int kt = 0; kt < KLL; ++kt)
    #pragma unroll
    for (int nt = 0; nt < 4; ++nt) {
      bf16x8 v = *reinterpret_cast<const bf16x8*>(whh_bf + ncol[nt] * HH + (KRR + kt) * 32 + hi * 8);
      *reinterpret_cast<bf16x8*>(wlds + (((w * 4 + nt) * KLL + kt) * 64 + l) * 8) = v;
    }

  // zero h state (16*512 = 8192 ushorts; 512 threads x 16)
  {
    bf16x8 z = {0, 0, 0, 0, 0, 0, 0, 0};
    *reinterpret_cast<bf16x8*>(hbuf + tid * 16) = z;
    *reinterpret_cast<bf16x8*>(hbuf + tid * 16 + 8) = z;
  }

  // per-batch-row pointers into out (xp source / output dest), col base = ncol[0]
  float* ptr[4];
  #pragma unroll
  for (int i = 0; i < 4; ++i)
    ptr[i] = out + (long)(bbase + hi * 4 + i) * TT * HH + ncol[0];

  char* hbc = reinterpret_cast<char*>(hbuf);
  long last_base = (long)BB * TT * HH;

  __syncthreads();

  #pragma unroll 1
  for (int t = 0; t < TT; ++t) {
    // xp loads (consumed in epilogue; latency hidden under MFMA loop)
    float xpv[4][4];
    #pragma unroll
    for (int i = 0; i < 4; ++i)
      #pragma unroll
      for (int nt = 0; nt < 4; ++nt)
        xpv[i][nt] = ptr[i][nt * 16];

    f32x4 acc[4];
    #pragma unroll
    for (int nt = 0; nt < 4; ++nt) acc[nt] = (f32x4){0.f, 0.f, 0.f, 0.f};

    bf16x8 wstr[KSS][4];
    #pragma unroll
    for (int kt = 0; kt < 16; ++kt) {
      // roll in streamed fragments 3 k-tiles ahead (L2-resident, same addr each step)
      if (kt >= KRR + KLL - 3 && kt < KRR + KLL - 3 + KSS) {
        int ks = kt - (KRR + KLL - 3);
        #pragma unroll
        for (int nt = 0; nt < 4; ++nt)
          wstr[ks][nt] = *reinterpret_cast<const bf16x8*>(
              whh_bf + ncol[nt] * HH + (KRR + KLL + ks) * 32 + hi * 8);
      }
      int abyte = (kt * 64 + hi * 16) ^ ((lo & 7) << 4);
      bf16x8 af = *reinterpret_cast<const bf16x8*>(hbc + lo * 1024 + abyte);
      #pragma unroll
      for (int nt = 0; nt < 4; ++nt) {
        bf16x8 bfr;
        if (kt < KRR)            bfr = wreg[kt][nt];
        else if (kt < KRR + KLL) bfr = *reinterpret_cast<const bf16x8*>(
                                         wlds + (((w * 4 + nt) * KLL + (kt - KRR)) * 64 + l) * 8);
        else                     bfr = wstr[kt - KRR - KLL][nt];
        acc[nt] = __builtin_amdgcn_mfma_f32_16x16x32_bf16(af, bfr, acc[nt], 0, 0, 0);
      }
    }
    __syncthreads();   // all hbuf reads complete before writes

    #pragma unroll
    for (int i = 0; i < 4; ++i) {
      bool valid = (t < len[i]);
      bool lastw = (t + 1 == len[i]);
      int brow = hi * 4 + i;
      #pragma unroll
      for (int nt = 0; nt < 4; ++nt) {
        float pre = acc[nt][i] + cpv[i][nt] + xpv[i][nt];
        pre = fminf(fmaxf(pre, -15.f), 15.f);
        float e = __expf(2.f * pre);
        float th = __builtin_fmaf(-2.f, __builtin_amdgcn_rcpf(e + 1.f), 1.f);  // tanh
        ptr[i][nt * 16] = valid ? th : 0.f;
        if (valid) {
          int cbyte = (ncol[nt] * 2) ^ ((brow & 7) << 4);
          *reinterpret_cast<unsigned short*>(hbc + brow * 1024 + cbyte) = f2bf(th);
        }
        if (lastw) {
          out[last_base + (long)(bbase + brow) * HH + ncol[nt]] = th;
        }
      }
      ptr[i] += HH;
    }
    __syncthreads();   // h writes visible before next step's reads
  }
}

// ---------------------------------------------------------------------------
extern "C" void kernel_launch(void* const* d_in, const int* in_sizes, int n_in,
                              void* d_out, int out_size, void* d_ws, size_t ws_size,
                              hipStream_t stream) {
  const float* x     = (const float*)d_in[0];
  const float* cons  = (const float*)d_in[1];
  const int*   lens  = (const int*)d_in[2];
  const float* W_ih  = (const float*)d_in[3];
  const float* b_ih  = (const float*)d_in[4];
  const float* W_hh  = (const float*)d_in[5];
  const float* b_hh  = (const float*)d_in[6];
  const float* W_ch  = (const float*)d_in[7];
  const float* b_ch  = (const float*)d_in[8];
  float* out = (float*)d_out;

  unsigned short* whh_bf = (unsigned short*)d_ws;                         // 512 KB
  unsigned short* wih_bf = (unsigned short*)((char*)d_ws + 512 * 1024);   // 256 KB
  float*          cpbuf  = (float*)((char*)d_ws + 768 * 1024);            // 256 KB

  k_prep<<<512, 256, 0, stream>>>(W_hh, W_ih, cons, W_ch, b_ch, b_hh, whh_bf, wih_bf, cpbuf);
  k_xp<<<2048, 256, 0, stream>>>(x, wih_bf, b_ih, out);
  k_rnn<<<8, 512, 0, stream>>>(out, whh_bf, cpbuf, lens);
}

// Round 3
// 5657.871 us; speedup vs baseline: 1.2476x; 1.2476x over previous
//
#include <hip/hip_runtime.h>
#include <hip/hip_bf16.h>

// Problem constants
#define BB 128
#define TT 1024
#define II 256
#define HH 512
#define CC 32

// W_hh residency split (16 k-tiles of 32 along K=512): ALL resident
#define KRR 12  // k-tiles in VGPRs (192 VGPRs, pinned)
#define KLL 4   // k-tiles in LDS (128 KB)

typedef short bf16x8 __attribute__((ext_vector_type(8)));
typedef float f32x4 __attribute__((ext_vector_type(4)));

__device__ __forceinline__ unsigned short f2bf(float f) {
  union { __hip_bfloat16 h; unsigned short u; } cv;
  cv.h = __float2bfloat16(f);
  return cv.u;
}
__device__ __forceinline__ float bflo(unsigned int u) {
  return __uint_as_float(u << 16);
}
__device__ __forceinline__ float bfhi(unsigned int u) {
  return __uint_as_float(u & 0xffff0000u);
}
__device__ __forceinline__ float tanh_fast(float x) {
  // tanh(x) = 1 - 2/(e^{2x}+1); __expf handles +-inf correctly
  float e = __expf(2.f * x);
  return __builtin_fmaf(-2.f, __builtin_amdgcn_rcpf(e + 1.f), 1.f);
}

// ---------------------------------------------------------------------------
// Prep: W_hh, W_ih -> bf16; cp[b][h] = cons@W_ch^T + b_ch + b_hh
// ---------------------------------------------------------------------------
__global__ void k_prep(const float* __restrict__ Whh, const float* __restrict__ Wih,
                       const float* __restrict__ cons, const float* __restrict__ Wch,
                       const float* __restrict__ bch, const float* __restrict__ bhh,
                       unsigned short* __restrict__ whh_bf, unsigned short* __restrict__ wih_bf,
                       float* __restrict__ cp) {
  int bid = blockIdx.x, tid = threadIdx.x;
  if (bid < 256) {                       // W_hh: 262144 elems
    int idx = bid * 1024 + tid * 4;
    float4 v = *reinterpret_cast<const float4*>(Whh + idx);
    ushort4 u = make_ushort4(f2bf(v.x), f2bf(v.y), f2bf(v.z), f2bf(v.w));
    *reinterpret_cast<ushort4*>(whh_bf + idx) = u;
  } else if (bid < 384) {                // W_ih: 131072 elems
    int idx = (bid - 256) * 1024 + tid * 4;
    float4 v = *reinterpret_cast<const float4*>(Wih + idx);
    ushort4 u = make_ushort4(f2bf(v.x), f2bf(v.y), f2bf(v.z), f2bf(v.w));
    *reinterpret_cast<ushort4*>(wih_bf + idx) = u;
  } else {                               // cp rows, b = bid-384
    int b = bid - 384;
    for (int h = tid; h < HH; h += 256) {
      float s = bch[h] + bhh[h];
      #pragma unroll
      for (int c = 0; c < CC; ++c) s += cons[b * CC + c] * Wch[h * CC + c];
      cp[b * HH + h] = s;
    }
  }
}

// ---------------------------------------------------------------------------
// xp GEMM: out[b][t][h] = x[b][t]·W_ih[h] + b_ih[h] + cp[b][h]
// Swapped-operand MFMA -> lane owns 1 x-row, 4 consecutive h-cols per acc reg.
// ---------------------------------------------------------------------------
__launch_bounds__(256, 2)
__global__ void k_xp(const float* __restrict__ x, const unsigned short* __restrict__ wih_bf,
                     const float* __restrict__ bih, const float* __restrict__ cp,
                     float* __restrict__ out) {
  __shared__ unsigned short As[64 * 64];    // 8 KB  [row][k] swizzled
  __shared__ unsigned short Ws[512 * 64];   // 64 KB [n][k] swizzled
  int tid = threadIdx.x;
  int w = tid >> 6, l = tid & 63, lo = l & 15, hi = l >> 4;
  int m0 = blockIdx.x * 64;
  int b = blockIdx.x >> 4;                  // 16 blocks per batch row

  f32x4 acc[32];
  #pragma unroll
  for (int i = 0; i < 32; ++i) acc[i] = (f32x4){0.f, 0.f, 0.f, 0.f};

  char* Asc = reinterpret_cast<char*>(As);
  char* Wsc = reinterpret_cast<char*>(Ws);

  for (int kit = 0; kit < 4; ++kit) {
    int k0 = kit * 64;
    __syncthreads();
    {
      int r = tid >> 2;
      int kq = (tid & 3) * 16;
      const float* src = x + (long)(m0 + r) * II + k0 + kq;
      #pragma unroll
      for (int q = 0; q < 4; ++q) {
        float4 v = *reinterpret_cast<const float4*>(src + q * 4);
        ushort4 u = make_ushort4(f2bf(v.x), f2bf(v.y), f2bf(v.z), f2bf(v.w));
        int byte = ((kq + q * 4) * 2) ^ ((r & 7) << 4);
        *reinterpret_cast<ushort4*>(Asc + r * 128 + byte) = u;
      }
    }
    {
      int rr = tid >> 3;
      int cc = (tid & 7) * 8;
      #pragma unroll
      for (int p = 0; p < 16; ++p) {
        int r = p * 32 + rr;
        uint4 v = *reinterpret_cast<const uint4*>(wih_bf + r * II + k0 + cc);
        int byte = (cc * 2) ^ ((r & 7) << 4);
        *reinterpret_cast<uint4*>(Wsc + r * 128 + byte) = v;
      }
    }
    __syncthreads();
    #pragma unroll
    for (int kt = 0; kt < 2; ++kt) {
      int kbyte = kt * 64 + hi * 16;
      int arow = w * 16 + lo;
      bf16x8 af = *reinterpret_cast<const bf16x8*>(Asc + arow * 128 + (kbyte ^ ((arow & 7) << 4)));
      #pragma unroll
      for (int nt = 0; nt < 32; ++nt) {
        int brow = nt * 16 + lo;
        bf16x8 bfr = *reinterpret_cast<const bf16x8*>(Wsc + brow * 128 + (kbyte ^ ((brow & 7) << 4)));
        acc[nt] = __builtin_amdgcn_mfma_f32_16x16x32_bf16(bfr, af, acc[nt], 0, 0, 0);
      }
    }
  }
  // epilogue: D[m=hcol][n=xrow]; lane: xrow = m0+w*16+lo, cols nt*16+hi*4+[0,4)
  long row = (long)(m0 + w * 16 + lo) * HH;
  #pragma unroll
  for (int nt = 0; nt < 32; ++nt) {
    int col = nt * 16 + hi * 4;
    float4 bb = *reinterpret_cast<const float4*>(bih + col);
    float4 cc = *reinterpret_cast<const float4*>(cp + b * HH + col);
    float4 o = make_float4(acc[nt][0] + bb.x + cc.x, acc[nt][1] + bb.y + cc.y,
                           acc[nt][2] + bb.z + cc.z, acc[nt][3] + bb.w + cc.w);
    *reinterpret_cast<float4*>(out + row + col) = o;
  }
}

// ---------------------------------------------------------------------------
// Recurrence: 8 WGs x 512 threads. WG owns batches [bg*16, bg*16+16).
// W_hh FULLY resident: 12 k-tiles in pinned VGPRs + 4 k-tiles in LDS.
// Swapped MFMA: lane = (batch=lo, 4 consecutive wcols per acc element).
// h double-buffered in LDS -> ONE barrier/step; out-stores deferred past it.
// ---------------------------------------------------------------------------
__launch_bounds__(512, 2)
__global__ void k_rnn(float* __restrict__ out,
                      const unsigned short* __restrict__ whh_bf,
                      const int* __restrict__ lengths) {
  __shared__ unsigned short hbuf[2][16 * 512];            // 2 x 16 KB
  __shared__ unsigned short wlds[8 * 4 * KLL * 64 * 8];   // 128 KB
  int tid = threadIdx.x;
  int w = tid >> 6, l = tid & 63, lo = l & 15, hi = l >> 4;
  int bbase = blockIdx.x * 16;

  int ncol[4];
  #pragma unroll
  for (int nt = 0; nt < 4; ++nt) ncol[nt] = w * 64 + nt * 16 + lo;
  int c0[4];
  #pragma unroll
  for (int nt = 0; nt < 4; ++nt) c0[nt] = w * 64 + nt * 16 + hi * 4;

  int len_b = lengths[bbase + lo];

  // W fragments resident in regs: kt in [0, KRR). Pin so the allocator cannot
  // rematerialize them as per-iteration global loads (round-1 failure mode).
  bf16x8 wreg[KRR][4];
  #pragma unroll
  for (int kt = 0; kt < KRR; ++kt)
    #pragma unroll
    for (int nt = 0; nt < 4; ++nt) {
      wreg[kt][nt] = *reinterpret_cast<const bf16x8*>(whh_bf + ncol[nt] * HH + kt * 32 + hi * 8);
      asm volatile("" : "+v"(wreg[kt][nt]));
    }

  // W fragments staged in LDS: kt in [KRR, KRR+KLL)
  #pragma unroll
  for (int kt = 0; kt < KLL; ++kt)
    #pragma unroll
    for (int nt = 0; nt < 4; ++nt) {
      bf16x8 v = *reinterpret_cast<const bf16x8*>(whh_bf + ncol[nt] * HH + (KRR + kt) * 32 + hi * 8);
      *reinterpret_cast<bf16x8*>(wlds + (((w * 4 + nt) * KLL + kt) * 64 + l) * 8) = v;
    }

  // zero h(0) -- BOTH 8-ushort halves of each thread's 16-ushort slice
  {
    bf16x8 z = {0, 0, 0, 0, 0, 0, 0, 0};
    *reinterpret_cast<bf16x8*>(&hbuf[0][tid * 16]) = z;
    *reinterpret_cast<bf16x8*>(&hbuf[0][tid * 16 + 8]) = z;
  }
  uint2 ph[4];                       // persistent packed-bf16 h (lane's 16 cols)
  #pragma unroll
  for (int nt = 0; nt < 4; ++nt) ph[nt] = make_uint2(0u, 0u);

  float* orow = out + (long)(bbase + lo) * TT * HH;
  float* lastrow = out + (long)BB * TT * HH + (long)(bbase + lo) * HH;

  const char* wc = reinterpret_cast<const char*>(wlds);
  unsigned short* RB = &hbuf[0][0];
  unsigned short* WB = &hbuf[1][0];

  __syncthreads();

  #pragma unroll 1
  for (int t = 0; t < TT; ++t) {
    // --- prefetch xp (HBM); pin issue before MFMA phase
    float4 xv[4];
    #pragma unroll
    for (int nt = 0; nt < 4; ++nt) xv[nt] = *reinterpret_cast<const float4*>(orow + c0[nt]);
    __builtin_amdgcn_sched_barrier(0);

    // --- MFMA phase: reads RB
    f32x4 acc[4];
    #pragma unroll
    for (int nt = 0; nt < 4; ++nt) acc[nt] = (f32x4){0.f, 0.f, 0.f, 0.f};
    const char* rb = reinterpret_cast<const char*>(RB);
    #pragma unroll
    for (int kt = 0; kt < KRR; ++kt) {
      int abyte = (kt * 64 + hi * 16) ^ ((lo & 7) << 4);
      bf16x8 af = *reinterpret_cast<const bf16x8*>(rb + lo * 1024 + abyte);
      #pragma unroll
      for (int nt = 0; nt < 4; ++nt)
        acc[nt] = __builtin_amdgcn_mfma_f32_16x16x32_bf16(wreg[kt][nt], af, acc[nt], 0, 0, 0);
    }
    #pragma unroll
    for (int kt = KRR; kt < 16; ++kt) {
      int abyte = (kt * 64 + hi * 16) ^ ((lo & 7) << 4);
      bf16x8 af = *reinterpret_cast<const bf16x8*>(rb + lo * 1024 + abyte);
      #pragma unroll
      for (int nt = 0; nt < 4; ++nt) {
        bf16x8 bw = *reinterpret_cast<const bf16x8*>(
            wc + (((w * 4 + nt) * KLL + (kt - KRR)) * 64 + l) * 16);
        acc[nt] = __builtin_amdgcn_mfma_f32_16x16x32_bf16(bw, af, acc[nt], 0, 0, 0);
      }
    }

    // --- epilogue: tanh, update persistent h, write h(t+1) to WB
    bool valid = (t < len_b);
    bool lastw = (t + 1 == len_b);
    uint2 thp[4];
    char* wbp = reinterpret_cast<char*>(WB) + lo * 1024;
    int swz = (lo & 7) << 4;
    #pragma unroll
    for (int nt = 0; nt < 4; ++nt) {
      float t0 = tanh_fast(acc[nt][0] + xv[nt].x);
      float t1 = tanh_fast(acc[nt][1] + xv[nt].y);
      float t2 = tanh_fast(acc[nt][2] + xv[nt].z);
      float t3 = tanh_fast(acc[nt][3] + xv[nt].w);
      thp[nt].x = (unsigned int)f2bf(t0) | ((unsigned int)f2bf(t1) << 16);
      thp[nt].y = (unsigned int)f2bf(t2) | ((unsigned int)f2bf(t3) << 16);
      if (valid) ph[nt] = thp[nt];
      *reinterpret_cast<uint2*>(wbp + ((w * 128 + nt * 32 + hi * 8) ^ swz)) = ph[nt];
    }
    __syncthreads();

    // --- deferred out stores (overlap next step's MFMA): masked output
    #pragma unroll
    for (int nt = 0; nt < 4; ++nt) {
      float4 o;
      o.x = valid ? bflo(thp[nt].x) : 0.f;
      o.y = valid ? bfhi(thp[nt].x) : 0.f;
      o.z = valid ? bflo(thp[nt].y) : 0.f;
      o.w = valid ? bfhi(thp[nt].y) : 0.f;
      *reinterpret_cast<float4*>(orow + c0[nt]) = o;
      if (lastw) *reinterpret_cast<float4*>(lastrow + c0[nt]) = o;
    }

    unsigned short* tmp = RB; RB = WB; WB = tmp;
    orow += HH;
  }
}

// ---------------------------------------------------------------------------
extern "C" void kernel_launch(void* const* d_in, const int* in_sizes, int n_in,
                              void* d_out, int out_size, void* d_ws, size_t ws_size,
                              hipStream_t stream) {
  const float* x     = (const float*)d_in[0];
  const float* cons  = (const float*)d_in[1];
  const int*   lens  = (const int*)d_in[2];
  const float* W_ih  = (const float*)d_in[3];
  const float* b_ih  = (const float*)d_in[4];
  const float* W_hh  = (const float*)d_in[5];
  const float* b_hh  = (const float*)d_in[6];
  const float* W_ch  = (const float*)d_in[7];
  const float* b_ch  = (const float*)d_in[8];
  float* out = (float*)d_out;

  unsigned short* whh_bf = (unsigned short*)d_ws;                         // 512 KB
  unsigned short* wih_bf = (unsigned short*)((char*)d_ws + 512 * 1024);   // 256 KB
  float*          cpbuf  = (float*)((char*)d_ws + 768 * 1024);            // 256 KB

  k_prep<<<512, 256, 0, stream>>>(W_hh, W_ih, cons, W_ch, b_ch, b_hh, whh_bf, wih_bf, cpbuf);
  k_xp<<<2048, 256, 0, stream>>>(x, wih_bf, b_ih, cpbuf, out);
  k_rnn<<<8, 512, 0, stream>>>(out, whh_bf, lens);
}